// Round 5
// baseline (197.312 us; speedup 1.0000x reference)
//
#include <hip/hip_runtime.h>
#include <math.h>

#define S_LEN    16
#define NTOK     64     // tokens, m = s*4 + b (lane dimension everywhere)
#define DMODEL   512
#define XB_COLS  2176   // x part (2048) + B part (128); z and C parts are dead code
#define ZX_COLS  2240   // XB_COLS + 64 dt columns
#define NCLASS   2513
#define FEATDIM  4096

// ---------------- k_xt: X (B,S,D) -> k-panel layout Xtp[(k/4)][m][4] -------------
__global__ void k_xt(const float* __restrict__ X, float* __restrict__ Xtp) {
    const int i = blockIdx.x * 256 + threadIdx.x;   // 8192 = 128 quads * 64 tokens
    const int kq = i >> 6, m = i & 63;
    const int row = (m & 3) * 16 + (m >> 2);        // inputs row b*16+s for token m=s*4+b
    const float4 v = *reinterpret_cast<const float4*>(X + (size_t)row * DMODEL + kq * 4);
    *reinterpret_cast<float4*>(Xtp + (size_t)i * 4) = v;
}

// ---------------- k_fpart: in_proj partial dots (K split by gridDim.y) ------------
// lane = token; wave = 2 columns; K-window = 128/gridDim.y quads.
// Depth-4 grouped loads: 12 independent float4 loads in flight per group.
__global__ __launch_bounds__(256) void k_fpart(const float* __restrict__ Xtp,
                                               const float* __restrict__ W,
                                               float* __restrict__ partF) {
    const int lane = threadIdx.x & 63;
    const int wv   = threadIdx.x >> 6;
    const int j0   = blockIdx.x * 8 + wv * 2;   // [0,2240)
    const int e0   = (j0     < XB_COLS) ? (2048 + j0)     : (2176 + j0);
    const int e1   = (j0 + 1 < XB_COLS) ? (2048 + j0 + 1) : (2176 + j0 + 1);
    const int nq   = 128 / gridDim.y;           // quads in this K-window
    const int q0   = blockIdx.y * nq;

    const float4* w0p = reinterpret_cast<const float4*>(W + (size_t)e0 * DMODEL) + q0;
    const float4* w1p = reinterpret_cast<const float4*>(W + (size_t)e1 * DMODEL) + q0;
    const float4* fp  = reinterpret_cast<const float4*>(Xtp) + (size_t)q0 * 64 + lane;

    float a0 = 0.f, a1 = 0.f;
    for (int g = 0; g < nq; g += 4) {
        float4 f[4], wa[4], wb[4];
#pragma unroll
        for (int i = 0; i < 4; ++i) {
            f[i]  = fp[(size_t)(g + i) * 64];
            wa[i] = w0p[g + i];
            wb[i] = w1p[g + i];
        }
#pragma unroll
        for (int i = 0; i < 4; ++i) {
            a0 += f[i].x * wa[i].x + f[i].y * wa[i].y + f[i].z * wa[i].z + f[i].w * wa[i].w;
            a1 += f[i].x * wb[i].x + f[i].y * wb[i].y + f[i].z * wb[i].z + f[i].w * wb[i].w;
        }
    }
    partF[((size_t)blockIdx.y * ZX_COLS + j0) * 64 + lane]     = a0;
    partF[((size_t)blockIdx.y * ZX_COLS + j0 + 1) * 64 + lane] = a1;
}

// ---------------- k_fepi: reduce partials + conv/silu + dt/dA ---------------------
__global__ __launch_bounds__(256) void k_fepi(const float* __restrict__ partF, int KF,
                                              const float* __restrict__ conv_w,
                                              const float* __restrict__ conv_b,
                                              const float* __restrict__ dt_bias,
                                              const float* __restrict__ A_log,
                                              float* __restrict__ u,
                                              float* __restrict__ aArr,
                                              float* __restrict__ dArr) {
    const int lane = threadIdx.x & 63;                 // token m
    const int j    = blockIdx.x * 4 + (threadIdx.x >> 6);
    float acc = 0.f;
    for (int kf = 0; kf < KF; ++kf)
        acc += partF[((size_t)kf * ZX_COLS + j) * 64 + lane];

    if (j < XB_COLS) {
        const float4 cwv = *reinterpret_cast<const float4*>(conv_w + j * 4);
        const float cb = conv_b[j];
        float wk[4];
        wk[0] = cwv.w;                  // cw[:,0] = conv_w[:,3]
        wk[1] = wk[0] + cwv.z;
        wk[2] = wk[1] + cwv.y;
        wk[3] = wk[2] + cwv.x;
#pragma unroll
        for (int k = 0; k < 4; ++k) {
            const float v = acc * wk[k] + cb;
            u[((size_t)k * NTOK + lane) * XB_COLS + j] = v / (1.f + expf(-v));
        }
    } else {
        const int h = j - XB_COLS;
        const float x = acc + dt_bias[h];
        const float d = (x > 20.f) ? x : log1pf(expf(x));
        dArr[lane * 64 + h] = d;
        aArr[lane * 64 + h] = expf(-d * expf(A_log[h]));
    }
}

// ---------------- k_feats: collapsed SSM -> feats in k-panel layout ---------------
__global__ __launch_bounds__(256) void k_feats(const float* __restrict__ u,
                                               const float* __restrict__ aArr,
                                               const float* __restrict__ dArr,
                                               float* __restrict__ feats_p) {
    const int t = blockIdx.x >> 2;
    const int b = blockIdx.x & 3;
    const int tid = threadIdx.x;
    const int K = 16 - t;          // unroll updates k = 0..K
    const int nvec = t + 5;        // (t+1) scan vectors + 4 unroll vectors

    __shared__ float q[16][64];
    __shared__ float cu[4][64];
    __shared__ float WV[20][32];
    __shared__ float Bv[20][128];

    if (tid < 64) {
        const int h = tid;
        const int mt = t * 4 + b;
        const float a   = aArr[mt * 64 + h];
        const float dtv = dArr[mt * 64 + h];
        float p = 1.f;
        float c3 = 0.f, c2 = 0.f, c1 = 0.f, c0 = 0.f, cs = 0.f;
        for (int j = 0; j <= K + 1; ++j) {     // p = a^j at loop head
            if (j <= K - 3) c3 += p;
            if (j == K - 2) c2 = p;
            if (j == K - 1) c1 = p;
            if (j == K)     c0 = p;
            if (j == K + 1) cs = p;
            p *= a;
        }
        cu[0][h] = dtv * c0;
        cu[1][h] = dtv * c1;
        cu[2][h] = dtv * c2;
        cu[3][h] = dtv * c3;
        float prod = 1.f;
        for (int s = t; s >= 0; --s) {
            const int ms = s * 4 + b;
            q[s][h] = cs * prod * dArr[ms * 64 + h];
            prod *= aArr[ms * 64 + h];
        }
    }
    __syncthreads();

    {   // head-reduced x vectors (32 wide each)
        const int i = tid & 31;
        const int vs = tid >> 5;
        for (int v = vs; v < nvec; v += 8) {
            float acc = 0.f;
            if (v <= t) {
                const float* base = u + (size_t)(v * 4 + b) * XB_COLS;
                for (int h = 0; h < 64; ++h) acc += q[v][h] * base[h * 32 + i];
            } else {
                const int kk = v - t - 1;
                const float* base = u + ((size_t)kk * NTOK + t * 4 + b) * XB_COLS;
                for (int h = 0; h < 64; ++h) acc += cu[kk][h] * base[h * 32 + i];
            }
            WV[v][i] = acc;
        }
    }
    for (int x = tid; x < nvec * 128; x += 256) {
        const int v = x >> 7, n = x & 127;
        size_t src;
        if (v <= t) src = (size_t)(v * 4 + b) * XB_COLS + 2048 + n;
        else        src = ((size_t)(v - t - 1) * NTOK + t * 4 + b) * XB_COLS + 2048 + n;
        Bv[v][n] = u[src];
    }
    __syncthreads();

    {   // rank-nvec outer products -> feats panel [k/4][64 rows][4]
        const int i  = tid >> 3;            // headdim index 0..31
        const int n0 = (tid & 7) * 16;      // state offset
        const int r  = b * 16 + t;          // output row (matches out layout)
        float acc[16];
#pragma unroll
        for (int nn = 0; nn < 16; ++nn) acc[nn] = 0.f;
        for (int v = 0; v < nvec; ++v) {
            const float wvv = WV[v][i];
#pragma unroll
            for (int nn = 0; nn < 16; ++nn) acc[nn] += wvv * Bv[v][n0 + nn];
        }
        float4* fp4 = reinterpret_cast<float4*>(feats_p);
#pragma unroll
        for (int qq = 0; qq < 4; ++qq) {
            const int kq = i * 32 + (tid & 7) * 4 + qq;
            float4 v4;
            v4.x = acc[qq * 4 + 0] * (1.f / 64.f);
            v4.y = acc[qq * 4 + 1] * (1.f / 64.f);
            v4.z = acc[qq * 4 + 2] * (1.f / 64.f);
            v4.w = acc[qq * 4 + 3] * (1.f / 64.f);
            fp4[(size_t)kq * 64 + r] = v4;
        }
    }
}

// ---------------- k_cls: classifier GEMM, register double-buffer, no LDS ----------
// 4 waves/block, 8 classes/wave (32/block). lane = token. Weight loads are
// wave-uniform (scalarizable to s_load); feats loads coalesced 1KB/instr.
// Double-buffered: load quad kq+1 while FMA-ing quad kq.
__global__ __launch_bounds__(256) void k_cls(const float* __restrict__ feats_p,
                                             const float* __restrict__ Wc,
                                             float* __restrict__ partialD) {
    const int tid  = threadIdx.x;
    const int lane = tid & 63;              // token / output row
    const int wv   = tid >> 6;
    const int cls0 = blockIdx.x * 32 + wv * 8;
    const int qPer = (FEATDIM / 4) / gridDim.y;     // even for all KC tiers
    const int kq0  = blockIdx.y * qPer;
    const int kqEnd = kq0 + qPer;

    const float4* fp4 = reinterpret_cast<const float4*>(feats_p);
    const float4* wr[8];
#pragma unroll
    for (int i = 0; i < 8; ++i) {
        int c = cls0 + i; if (c > NCLASS - 1) c = NCLASS - 1;
        wr[i] = reinterpret_cast<const float4*>(Wc + (size_t)c * FEATDIM);
    }

    float acc[8];
#pragma unroll
    for (int i = 0; i < 8; ++i) acc[i] = 0.f;

    float4 fA, fB, wA[8], wB[8];
    fA = fp4[(size_t)kq0 * 64 + lane];
#pragma unroll
    for (int i = 0; i < 8; ++i) wA[i] = wr[i][kq0];

    for (int kq = kq0; kq < kqEnd; kq += 2) {
        // prefetch kq+1 (always < kqEnd since qPer is even)
        fB = fp4[(size_t)(kq + 1) * 64 + lane];
#pragma unroll
        for (int i = 0; i < 8; ++i) wB[i] = wr[i][kq + 1];
#pragma unroll
        for (int i = 0; i < 8; ++i)
            acc[i] += fA.x * wA[i].x + fA.y * wA[i].y + fA.z * wA[i].z + fA.w * wA[i].w;

        // prefetch kq+2 (clamped; extra load harmless)
        int kn = kq + 2; if (kn >= kqEnd) kn = kqEnd - 1;
        fA = fp4[(size_t)kn * 64 + lane];
#pragma unroll
        for (int i = 0; i < 8; ++i) wA[i] = wr[i][kn];
#pragma unroll
        for (int i = 0; i < 8; ++i)
            acc[i] += fB.x * wB[i].x + fB.y * wB[i].y + fB.z * wB[i].z + fB.w * wB[i].w;
    }

#pragma unroll
    for (int i = 0; i < 8; ++i) {
        const int c = cls0 + i;
        if (c < NCLASS)
            partialD[((size_t)blockIdx.y * NCLASS + c) * 64 + lane] = acc[i];
    }
}

// ---------------- k_out: reduce split-K partials + bias -> out --------------------
__global__ void k_out(const float* __restrict__ partialD, const float* __restrict__ cls_b,
                      float* __restrict__ out, int KC) {
    const int r  = threadIdx.x & 63;
    const int cl = threadIdx.x >> 6;
    const int c  = blockIdx.x * 4 + cl;
    if (c >= NCLASS) return;
    float s = cls_b[c];
    for (int kc = 0; kc < KC; ++kc)
        s += partialD[((size_t)kc * NCLASS + c) * 64 + r];
    out[(size_t)r * NCLASS + c] = s;
}

// ------------------------------------------------------------------------------
extern "C" void kernel_launch(void* const* d_in, const int* in_sizes, int n_in,
                              void* d_out, int out_size, void* d_ws, size_t ws_size,
                              hipStream_t stream) {
    const float* inputs  = (const float*)d_in[0];
    const float* in_proj = (const float*)d_in[1];
    const float* conv_w  = (const float*)d_in[2];
    const float* conv_b  = (const float*)d_in[3];
    const float* dt_bias = (const float*)d_in[4];
    const float* A_log   = (const float*)d_in[5];
    const float* cls_w   = (const float*)d_in[6];
    const float* cls_b   = (const float*)d_in[7];
    float* out = (float*)d_out;

    float* ws = (float*)d_ws;
    float* aArr    = ws;               //   4096
    float* dArr    = ws + 4096;        //   4096
    float* Xtp     = ws + 8192;        //  32768
    float* feats_p = ws + 40960;       // 262144
    float* scr     = ws + 303104;
    float* u       = scr;              // 557056 (dead after k_feats)
    float* partF   = scr + 557056;     // KF*2240*64 (dead after k_fepi)
    float* partialD = scr;             // KC*2513*64 (written after k_feats)

    // tiers: bytes = (303104 + max(557056 + KF*143360, KC*160832)) * 4
    int KC, KF;
    if      (ws_size >= 11505664u) { KC = 16; KF = 8; }
    else if (ws_size >=  8028160u) { KC = 8;  KF = 8; }
    else if (ws_size >=  5734400u) { KC = 4;  KF = 4; }
    else                           { KC = 2;  KF = 2; }

    k_xt    <<<32, 256, 0, stream>>>(inputs, Xtp);
    k_fpart <<<dim3(280, KF), 256, 0, stream>>>(Xtp, in_proj, partF);
    k_fepi  <<<560, 256, 0, stream>>>(partF, KF, conv_w, conv_b, dt_bias, A_log,
                                      u, aArr, dArr);
    k_feats <<<64, 256, 0, stream>>>(u, aArr, dArr, feats_p);
    k_cls   <<<dim3(79, KC), 256, 0, stream>>>(feats_p, cls_w, partialD);
    k_out   <<<629, 256, 0, stream>>>(partialD, cls_b, out, KC);
}

// Round 8
// 118.277 us; speedup vs baseline: 1.6682x; 1.6682x over previous
//
#include <hip/hip_runtime.h>
#include <math.h>

#define S_LEN    16
#define NTOK     64     // tokens, m = s*4 + b (lane dimension everywhere)
#define DMODEL   512
#define XB_COLS  2176   // x part (2048) + B part (128); z and C parts are dead code
#define ZX_COLS  2240   // XB_COLS + 64 dt columns
#define NCLASS   2513
#define FEATDIM  4096

typedef float f16v __attribute__((ext_vector_type(16)));

// launder a wave-uniform pointer into SGPRs (divergence analysis can't prove
// threadIdx>>6-derived values uniform; readfirstlane forces scalar allocation)
__device__ __forceinline__ const float* uptr(const float* p) {
    const uint64_t u = (uint64_t)p;
    const uint32_t lo = __builtin_amdgcn_readfirstlane((uint32_t)u);
    const uint32_t hi = __builtin_amdgcn_readfirstlane((uint32_t)(u >> 32));
    return (const float*)(((uint64_t)hi << 32) | (uint64_t)lo);
}

// Self-contained 64-float (256B) scalar fetch: issue 4x s_load_dwordx16 and
// drain INSIDE one asm statement. At asm exit the SGPRs hold landed data, so
// any compiler-inserted copies afterwards are safe (the round-7 hazard was
// copies of in-flight s_load destinations between split issue/wait asms).
#define SLOADW(r0, r1, r2, r3, p)                                   \
    asm volatile("s_load_dwordx16 %0, %4, 0x0\n\t"                  \
                 "s_load_dwordx16 %1, %4, 0x40\n\t"                 \
                 "s_load_dwordx16 %2, %4, 0x80\n\t"                 \
                 "s_load_dwordx16 %3, %4, 0xC0\n\t"                 \
                 "s_waitcnt lgkmcnt(0)"                             \
                 : "=&s"(r0), "=&s"(r1), "=&s"(r2), "=&s"(r3)       \
                 : "s"(p))

#define DOTW(A, R, a, b, c, d)                                      \
    A += a.x*R[0]  + a.y*R[1]  + a.z*R[2]  + a.w*R[3]               \
       + b.x*R[4]  + b.y*R[5]  + b.z*R[6]  + b.w*R[7]               \
       + c.x*R[8]  + c.y*R[9]  + c.z*R[10] + c.w*R[11]              \
       + d.x*R[12] + d.y*R[13] + d.z*R[14] + d.w*R[15]

// 64-float k-subtile of the streaming operand applied to one accumulator
#define SUBTILE64(ACC, WP)                                          \
    do {                                                            \
        f16v W0, W1, W2, W3;                                        \
        SLOADW(W0, W1, W2, W3, WP);                                 \
        DOTW(ACC, W0, q0,  q1,  q2,  q3);                           \
        DOTW(ACC, W1, q4,  q5,  q6,  q7);                           \
        DOTW(ACC, W2, q8,  q9,  q10, q11);                          \
        DOTW(ACC, W3, q12, q13, q14, q15);                          \
    } while (0)

#define LOADQ16(EXPR)                                               \
    float4 q0  = (EXPR(0)),  q1  = (EXPR(1)),  q2  = (EXPR(2)),     \
           q3  = (EXPR(3)),  q4  = (EXPR(4)),  q5  = (EXPR(5)),     \
           q6  = (EXPR(6)),  q7  = (EXPR(7)),  q8  = (EXPR(8)),     \
           q9  = (EXPR(9)),  q10 = (EXPR(10)), q11 = (EXPR(11)),    \
           q12 = (EXPR(12)), q13 = (EXPR(13)), q14 = (EXPR(14)),    \
           q15 = (EXPR(15))

// ---------------- k_fpart: in_proj partial dots (X transpose fused) --------------
// grid (280, KF/4) x 256 thr. wave: 8 cols x 64 tokens x (512/KF)-k chunk.
// lane = token m; X rows read strided from L2 (X is 128KB, L2-resident).
__global__ __launch_bounds__(256) void k_fpart(const float* __restrict__ X,
                                               const float* __restrict__ W,
                                               float* __restrict__ partF) {
    const int lane  = threadIdx.x & 63;
    const int wv    = threadIdx.x >> 6;
    const int KF    = gridDim.y * 4;
    const int kf    = blockIdx.y * 4 + wv;      // 0..KF-1
    const int jbase = blockIdx.x * 8;           // col group (2240 = 280*8 exact)
    const int nsub  = 8 / gridDim.y / 4;        // 64-float subtiles: KF=8 -> 1, KF=4 -> 2
    const int chunk = 512 / KF;                 // floats per k-chunk

    const int row = (lane & 3) * 16 + (lane >> 2);  // inputs row b*16+s for token m=lane
    const float4* xr = reinterpret_cast<const float4*>(X + (size_t)row * DMODEL);

    int erow[8];
#pragma unroll
    for (int c = 0; c < 8; ++c) {
        const int j = jbase + c;
        erow[c] = (j < XB_COLS) ? (2048 + j) : (2176 + j);
    }

    float acc[8] = {0.f,0.f,0.f,0.f,0.f,0.f,0.f,0.f};

    for (int s = 0; s < nsub; ++s) {
        const int kq0 = kf * (chunk / 4) + s * 16;
#define XQ(i) xr[kq0 + (i)]
        LOADQ16(XQ);
#undef XQ
#pragma unroll
        for (int c = 0; c < 8; ++c) {
            const float* wp = uptr(W + (size_t)erow[c] * DMODEL + kf * chunk + s * 64);
            SUBTILE64(acc[c], wp);
        }
    }
#pragma unroll
    for (int c = 0; c < 8; ++c)
        partF[((size_t)kf * ZX_COLS + jbase + c) * 64 + lane] = acc[c];
}

// ---------------- k_fepi: reduce partials + conv/silu + dt/dA ---------------------
__global__ __launch_bounds__(256) void k_fepi(const float* __restrict__ partF, int KF,
                                              const float* __restrict__ conv_w,
                                              const float* __restrict__ conv_b,
                                              const float* __restrict__ dt_bias,
                                              const float* __restrict__ A_log,
                                              float* __restrict__ u,
                                              float* __restrict__ aArr,
                                              float* __restrict__ dArr) {
    const int lane = threadIdx.x & 63;                 // token m
    const int j    = blockIdx.x * 4 + (threadIdx.x >> 6);
    float acc = 0.f;
    for (int kf = 0; kf < KF; ++kf)
        acc += partF[((size_t)kf * ZX_COLS + j) * 64 + lane];

    if (j < XB_COLS) {
        const float4 cwv = *reinterpret_cast<const float4*>(conv_w + j * 4);
        const float cb = conv_b[j];
        float wk[4];
        wk[0] = cwv.w;                  // cw[:,0] = conv_w[:,3]
        wk[1] = wk[0] + cwv.z;
        wk[2] = wk[1] + cwv.y;
        wk[3] = wk[2] + cwv.x;
#pragma unroll
        for (int k = 0; k < 4; ++k) {
            const float v = acc * wk[k] + cb;
            u[((size_t)k * NTOK + lane) * XB_COLS + j] = v / (1.f + expf(-v));
        }
    } else {
        const int h = j - XB_COLS;
        const float x = acc + dt_bias[h];
        const float d = (x > 20.f) ? x : log1pf(expf(x));
        dArr[lane * 64 + h] = d;
        aArr[lane * 64 + h] = expf(-d * expf(A_log[h]));
    }
}

// ---------------- k_feats: collapsed SSM -> feats in k-panel layout ---------------
__global__ __launch_bounds__(256) void k_feats(const float* __restrict__ u,
                                               const float* __restrict__ aArr,
                                               const float* __restrict__ dArr,
                                               float* __restrict__ feats_p) {
    const int t = blockIdx.x >> 2;
    const int b = blockIdx.x & 3;
    const int tid = threadIdx.x;
    const int K = 16 - t;          // unroll updates k = 0..K
    const int nvec = t + 5;        // (t+1) scan vectors + 4 unroll vectors

    __shared__ float q[16][64];
    __shared__ float cu[4][64];
    __shared__ float WV[20][32];
    __shared__ float Bv[20][128];

    if (tid < 64) {
        const int h = tid;
        const int mt = t * 4 + b;
        const float a   = aArr[mt * 64 + h];
        const float dtv = dArr[mt * 64 + h];
        float p = 1.f;
        float c3 = 0.f, c2 = 0.f, c1 = 0.f, c0 = 0.f, cs = 0.f;
        for (int j = 0; j <= K + 1; ++j) {     // p = a^j at loop head
            if (j <= K - 3) c3 += p;
            if (j == K - 2) c2 = p;
            if (j == K - 1) c1 = p;
            if (j == K)     c0 = p;
            if (j == K + 1) cs = p;
            p *= a;
        }
        cu[0][h] = dtv * c0;
        cu[1][h] = dtv * c1;
        cu[2][h] = dtv * c2;
        cu[3][h] = dtv * c3;
        float prod = 1.f;
        for (int s = t; s >= 0; --s) {
            const int ms = s * 4 + b;
            q[s][h] = cs * prod * dArr[ms * 64 + h];
            prod *= aArr[ms * 64 + h];
        }
    }
    __syncthreads();

    {   // head-reduced x vectors (32 wide each)
        const int i = tid & 31;
        const int vs = tid >> 5;
        for (int v = vs; v < nvec; v += 8) {
            float acc = 0.f;
            if (v <= t) {
                const float* base = u + (size_t)(v * 4 + b) * XB_COLS;
                for (int h = 0; h < 64; ++h) acc += q[v][h] * base[h * 32 + i];
            } else {
                const int kk = v - t - 1;
                const float* base = u + ((size_t)kk * NTOK + t * 4 + b) * XB_COLS;
                for (int h = 0; h < 64; ++h) acc += cu[kk][h] * base[h * 32 + i];
            }
            WV[v][i] = acc;
        }
    }
    for (int x = tid; x < nvec * 128; x += 256) {
        const int v = x >> 7, n = x & 127;
        size_t src;
        if (v <= t) src = (size_t)(v * 4 + b) * XB_COLS + 2048 + n;
        else        src = ((size_t)(v - t - 1) * NTOK + t * 4 + b) * XB_COLS + 2048 + n;
        Bv[v][n] = u[src];
    }
    __syncthreads();

    {   // rank-nvec outer products -> feats panel [k/4][64 rows][4]
        const int i  = tid >> 3;            // headdim index 0..31
        const int n0 = (tid & 7) * 16;      // state offset
        const int r  = b * 16 + t;          // output row (matches out layout)
        float acc[16];
#pragma unroll
        for (int nn = 0; nn < 16; ++nn) acc[nn] = 0.f;
        for (int v = 0; v < nvec; ++v) {
            const float wvv = WV[v][i];
#pragma unroll
            for (int nn = 0; nn < 16; ++nn) acc[nn] += wvv * Bv[v][n0 + nn];
        }
        float4* fp4 = reinterpret_cast<float4*>(feats_p);
#pragma unroll
        for (int qq = 0; qq < 4; ++qq) {
            const int kq = i * 32 + (tid & 7) * 4 + qq;
            float4 v4;
            v4.x = acc[qq * 4 + 0] * (1.f / 64.f);
            v4.y = acc[qq * 4 + 1] * (1.f / 64.f);
            v4.z = acc[qq * 4 + 2] * (1.f / 64.f);
            v4.w = acc[qq * 4 + 3] * (1.f / 64.f);
            fp4[(size_t)kq * 64 + r] = v4;
        }
    }
}

// ---------------- k_cls: classifier GEMM, weights via safe s_load chunks ----------
// grid (315, KC/4) x 256 thr. wave: 8 classes x 64 tokens x (4096/KC)-k chunk.
// Inner: 16 coalesced feats float4 (VMEM, L2-hot) + per-class 256B scalar fetch
// + 64 v_fma (SGPR weight x VGPR feat). No LDS.
__global__ __launch_bounds__(256) void k_cls(const float* __restrict__ feats_p,
                                             const float* __restrict__ Wc,
                                             float* __restrict__ partialD) {
    const int lane  = threadIdx.x & 63;
    const int wv    = threadIdx.x >> 6;
    const int KC    = gridDim.y * 4;
    const int kc    = blockIdx.y * 4 + wv;      // 0..KC-1
    const int cbase = blockIdx.x * 8;           // 315*8 = 2520 >= 2513
    const int chunk = FEATDIM / KC;             // floats per k-chunk
    const int nsub  = chunk / 64;               // 64-float subtiles

    int crow[8];
#pragma unroll
    for (int c = 0; c < 8; ++c) {
        int cr = cbase + c; if (cr > NCLASS - 1) cr = NCLASS - 1;
        crow[c] = cr;
    }

    const float4* fp4 = reinterpret_cast<const float4*>(feats_p);
    float acc[8] = {0.f,0.f,0.f,0.f,0.f,0.f,0.f,0.f};

    for (int s = 0; s < nsub; ++s) {
        const int kq0 = kc * (chunk / 4) + s * 16;
#define FQ(i) fp4[(size_t)(kq0 + (i)) * 64 + lane]
        LOADQ16(FQ);
#undef FQ
#pragma unroll
        for (int c = 0; c < 8; ++c) {
            const float* wp = uptr(Wc + (size_t)crow[c] * FEATDIM + kc * chunk + s * 64);
            SUBTILE64(acc[c], wp);
        }
    }

#pragma unroll
    for (int c = 0; c < 8; ++c) {
        const int cr = cbase + c;
        if (cr < NCLASS)
            partialD[((size_t)kc * NCLASS + cr) * 64 + lane] = acc[c];
    }
}

// ---------------- k_out: reduce split-K partials + bias -> out --------------------
__global__ void k_out(const float* __restrict__ partialD, const float* __restrict__ cls_b,
                      float* __restrict__ out, int KC) {
    const int r  = threadIdx.x & 63;
    const int cl = threadIdx.x >> 6;
    const int c  = blockIdx.x * 4 + cl;
    if (c >= NCLASS) return;
    float s = cls_b[c];
    for (int kc = 0; kc < KC; ++kc)
        s += partialD[((size_t)kc * NCLASS + c) * 64 + r];
    out[(size_t)r * NCLASS + c] = s;
}

// ------------------------------------------------------------------------------
extern "C" void kernel_launch(void* const* d_in, const int* in_sizes, int n_in,
                              void* d_out, int out_size, void* d_ws, size_t ws_size,
                              hipStream_t stream) {
    const float* inputs  = (const float*)d_in[0];
    const float* in_proj = (const float*)d_in[1];
    const float* conv_w  = (const float*)d_in[2];
    const float* conv_b  = (const float*)d_in[3];
    const float* dt_bias = (const float*)d_in[4];
    const float* A_log   = (const float*)d_in[5];
    const float* cls_w   = (const float*)d_in[6];
    const float* cls_b   = (const float*)d_in[7];
    float* out = (float*)d_out;

    float* ws = (float*)d_ws;
    float* aArr    = ws;               //   4096
    float* dArr    = ws + 4096;        //   4096
    float* feats_p = ws + 8192;        // 262144
    float* scr     = ws + 270336;
    float* u       = scr;              // 557056 (dead after k_feats)
    float* partF   = scr + 557056;     // KF*2240*64 (dead after k_fepi)
    float* partialD = scr;             // KC*2513*64 (written after k_feats)

    // tiers: bytes = (270336 + max(557056 + KF*143360, KC*160832)) * 4
    //   KC=16,KF=8 -> 11,374,592   KC=8,KF=8 -> 7,897,088   KC=4,KF=4 -> 5,603,328
    int KC, KF;
    if      (ws_size >= 11374592u) { KC = 16; KF = 8; }
    else if (ws_size >=  7897088u) { KC = 8;  KF = 8; }
    else                           { KC = 4;  KF = 4; }

    k_fpart <<<dim3(280, KF / 4), 256, 0, stream>>>(inputs, in_proj, partF);
    k_fepi  <<<560, 256, 0, stream>>>(partF, KF, conv_w, conv_b, dt_bias, A_log,
                                      u, aArr, dArr);
    k_feats <<<64, 256, 0, stream>>>(u, aArr, dArr, feats_p);
    k_cls   <<<dim3(315, KC / 4), 256, 0, stream>>>(feats_p, cls_w, partialD);
    k_out   <<<629, 256, 0, stream>>>(partialD, cls_b, out, KC);
}